// Round 12
// baseline (213.655 us; speedup 1.0000x reference)
//
#include <hip/hip_runtime.h>
#include <hip/hip_bf16.h>
#include <math.h>

#define SEQ   168
#define BATCH 4096
#define NOUT  9
#define NBLK  256        // BATCH / 16

typedef short bf16x8 __attribute__((ext_vector_type(8)));
typedef float f32x4  __attribute__((ext_vector_type(4)));

#define MFMA(a,b,c) __builtin_amdgcn_mfma_f32_16x16x32_bf16((a),(b),(c),0,0,0)

static __device__ __forceinline__ float bf2f(unsigned short h){
    unsigned int u = ((unsigned int)h) << 16;
    return __builtin_bit_cast(float, u);
}
static __device__ __forceinline__ unsigned short f2bf(float f){  // HW RNE
    return __builtin_bit_cast(unsigned short, __float2bfloat16(f));
}
// weight split: hi = RNE(f), lo = trunc(residual) -> hi+lo == f to ~2^-18 rel
static __device__ __forceinline__ void splitf(float f, unsigned short& hi, unsigned short& lo){
    hi = f2bf(f);
    float r = f - bf2f(hi);
    lo = (unsigned short)(__builtin_bit_cast(unsigned int, r) >> 16);
}
static __device__ __forceinline__ float sigf(float x){
    return __builtin_amdgcn_rcpf(1.0f + __expf(-x));
}
static __device__ __forceinline__ float tanhf_(float x){
    float r = __builtin_amdgcn_rcpf(1.0f + __expf(2.0f * x));
    return fmaf(-2.0f, r, 1.0f);
}
static __device__ __forceinline__ bf16x8 ldfrag(const unsigned short* p){
    const uint4 q = *reinterpret_cast<const uint4*>(p);
    return __builtin_bit_cast(bf16x8, q);
}

// group-local sense-reversing barrier over 4 waves; last arriver posts `tickval`
static __device__ __forceinline__ void gbar(int* cnt, int* phs, int* done,
                                            int tickval, int& ph, int lane){
    asm volatile("s_waitcnt lgkmcnt(0)" ::: "memory");
    if (lane == 0){
        int old = __hip_atomic_fetch_add(cnt, 1, __ATOMIC_ACQ_REL,
                                         __HIP_MEMORY_SCOPE_WORKGROUP);
        if (old == 3){
            *cnt = 0;
            __hip_atomic_store(done, tickval, __ATOMIC_RELEASE,
                               __HIP_MEMORY_SCOPE_WORKGROUP);
            __hip_atomic_store(phs, ph ^ 1, __ATOMIC_RELEASE,
                               __HIP_MEMORY_SCOPE_WORKGROUP);
        }
    }
    while (__hip_atomic_load(phs, __ATOMIC_ACQUIRE,
                             __HIP_MEMORY_SCOPE_WORKGROUP) == ph)
        __builtin_amdgcn_s_sleep(1);
    ph ^= 1;
}
static __device__ __forceinline__ void wait_ge(int* done, int need){
    if (__hip_atomic_load(done, __ATOMIC_ACQUIRE, __HIP_MEMORY_SCOPE_WORKGROUP) >= need) return;
    do { __builtin_amdgcn_s_sleep(1); }
    while (__hip_atomic_load(done, __ATOMIC_ACQUIRE, __HIP_MEMORY_SCOPE_WORKGROUP) < need);
}

// 512 threads, two free-running wave groups, software-pipelined across gbar:
//   Group 0 (waves 0-3): layer0 tick t in [0,SEQ). Post-gbar path = read h0 frag
//     -> 16 h-MFMAs -> nonlin -> write. The x-side (bias + 8 x-MFMAs for tick
//     t+1) is precomputed pre-gbar into acc_pre (x triple-buffered, 2 ahead).
//   Group 1 (waves 4-7): layer1 tick t in [1,SEQ] (step t-1). Head for step t-2
//     (t>=2) reuses the live A1H frags (= h1_{t-2}); epilogue emits step SEQ-1.
//     Input-side (bias + 16 h0-MFMAs for tick t+1) precomputed pre-gbar.
// h0 triple-buffered; guards identical to the proven r10 skeleton.
__global__ __launch_bounds__(512, 2)
void lstm_fused(const float* __restrict__ x,
                const float* __restrict__ Wih0, const float* __restrict__ Whh0,
                const float* __restrict__ bih0, const float* __restrict__ bhh0,
                const float* __restrict__ Wih1, const float* __restrict__ Whh1,
                const float* __restrict__ bih1, const float* __restrict__ bhh1,
                const float* __restrict__ Wout, const float* __restrict__ bout,
                float* __restrict__ out)
{
    __shared__ __align__(16) unsigned short sXH[3][16][72];   // x hi, triple buf
    __shared__ __align__(16) unsigned short sH0H[3][16][72];  // h0 hi, triple buf
    __shared__ __align__(16) unsigned short sH1H[2][16][72];  // h1 hi
    __shared__ int sync[8];  // [0,1]=cnt, [2,3]=phase, [4]=l0_done, [5]=l1_done

    const int tid  = threadIdx.x;
    const int half = tid >> 8;
    const int w2   = (tid >> 6) & 3;
    const int l    = tid & 63;
    const int lr   = l & 15;
    const int g    = l >> 4;
    const int r0   = blockIdx.x * 16;
    const int cg   = w2 * 16 + lr;

    if (tid < 8) sync[tid] = (tid == 4) ? -1 : 0;

    for (int i = tid; i < (int)(3*16*72/2); i += 512){
        ((unsigned int*)sXH)[i]  = 0u;
        ((unsigned int*)sH0H)[i] = 0u;
    }
    for (int i = tid; i < (int)(2*16*72/2); i += 512)
        ((unsigned int*)sH1H)[i] = 0u;
    __syncthreads();
    // stage x_0 -> buf 0, x_1 -> buf 1
    if (tid < 96){
        const int row = (tid * 4) / 24, col = (tid * 4) % 24;
        const float4 v0 = *reinterpret_cast<const float4*>(&x[(size_t)r0 * 24 + tid * 4]);
        const float4 v1 = *reinterpret_cast<const float4*>(&x[((size_t)BATCH + r0) * 24 + tid * 4]);
        ushort4 w0 = { f2bf(v0.x), f2bf(v0.y), f2bf(v0.z), f2bf(v0.w) };
        ushort4 w1 = { f2bf(v1.x), f2bf(v1.y), f2bf(v1.z), f2bf(v1.w) };
        *reinterpret_cast<ushort4*>(&sXH[0][row][col]) = w0;
        *reinterpret_cast<ushort4*>(&sXH[1][row][col]) = w1;
    }
    __syncthreads();

    if (half == 0){
        // ================= LAYER 0 waves (group 0) =================
        bf16x8 B0H[4][3], B0L[4][3];   // ks0 = Wih0 (K=24 pad 32), ks1,2 = Whh0
        #pragma unroll
        for (int gt = 0; gt < 4; ++gt){
            const int c = gt * 64 + cg;
            bf16x8 bh = {0,0,0,0,0,0,0,0}, bl = {0,0,0,0,0,0,0,0};
            if (g < 3){
                const float* pw = &Wih0[c * 24 + g * 8];
                #pragma unroll
                for (int j = 0; j < 8; ++j){ unsigned short hh, ll; splitf(pw[j], hh, ll); bh[j]=(short)hh; bl[j]=(short)ll; }
            }
            B0H[gt][0] = bh; B0L[gt][0] = bl;
            #pragma unroll
            for (int ks = 0; ks < 2; ++ks){
                bf16x8 ch, cl;
                const float* pw = &Whh0[c * 64 + ks * 32 + g * 8];
                #pragma unroll
                for (int j = 0; j < 8; ++j){ unsigned short hh, ll; splitf(pw[j], hh, ll); ch[j]=(short)hh; cl[j]=(short)ll; }
                B0H[gt][1+ks] = ch; B0L[gt][1+ks] = cl;
            }
        }
        float b0[4];
        #pragma unroll
        for (int gt = 0; gt < 4; ++gt) b0[gt] = bih0[gt*64 + cg] + bhh0[gt*64 + cg];

        // pre-loop: acc_pre for tick 0 = bias + x_0 MFMAs
        f32x4 acc_pre[4];
        {
            const bf16x8 Ax = ldfrag(&sXH[0][lr][g*8]);
            #pragma unroll
            for (int gt = 0; gt < 4; ++gt){ f32x4 a = {b0[gt],b0[gt],b0[gt],b0[gt]}; acc_pre[gt] = a; }
            #pragma unroll
            for (int gt = 0; gt < 4; ++gt) acc_pre[gt] = MFMA(Ax, B0H[gt][0], acc_pre[gt]);
            #pragma unroll
            for (int gt = 0; gt < 4; ++gt) acc_pre[gt] = MFMA(Ax, B0L[gt][0], acc_pre[gt]);
        }

        const float* xfp = x + ((size_t)2 * BATCH + r0) * 24 + tid * 4;  // x_{t+2}
        float c0[4] = {0,0,0,0};
        int ph = 0;
        int pw = 0, pr = 2;        // h0: write t%3, read (t-1)%3
        int bxr = 1, bxw = 2;      // x: frag-read (t+1)%3, stage-write (t+2)%3
        for (int t = 0; t < SEQ; ++t){
            // issue global prefetch of x_{t+2} early
            const bool ldx = (tid < 96) && (t + 2 < SEQ);
            float4 pref;
            if (ldx){ pref = *reinterpret_cast<const float4*>(xfp); xfp += (size_t)BATCH * 24; }

            // critical path: h0_{t-1} frags -> 16 h-MFMAs -> nonlin
            bf16x8 A0H[2];
            A0H[0] = ldfrag(&sH0H[pr][lr][g*8]);
            A0H[1] = ldfrag(&sH0H[pr][lr][32 + g*8]);
            f32x4 a0[4];
            #pragma unroll
            for (int gt = 0; gt < 4; ++gt) a0[gt] = acc_pre[gt];
            #pragma unroll
            for (int ks = 0; ks < 2; ++ks){
                #pragma unroll
                for (int gt = 0; gt < 4; ++gt) a0[gt] = MFMA(A0H[ks], B0H[gt][1+ks], a0[gt]);
                #pragma unroll
                for (int gt = 0; gt < 4; ++gt) a0[gt] = MFMA(A0H[ks], B0L[gt][1+ks], a0[gt]);
            }
            unsigned short hh[4];
            #pragma unroll
            for (int i = 0; i < 4; ++i){
                const float ig = sigf(a0[0][i]);
                const float fg = sigf(a0[1][i]);
                const float gg = tanhf_(a0[2][i]);
                const float og = sigf(a0[3][i]);
                c0[i] = fg * c0[i] + ig * gg;
                hh[i] = f2bf(og * tanhf_(c0[i]));
            }
            // pre-work for tick t+1: x-side MFMAs (recurrence-free)
            if (t + 1 < SEQ){
                const bf16x8 Axn = ldfrag(&sXH[bxr][lr][g*8]);
                #pragma unroll
                for (int gt = 0; gt < 4; ++gt){ f32x4 a = {b0[gt],b0[gt],b0[gt],b0[gt]}; acc_pre[gt] = a; }
                #pragma unroll
                for (int gt = 0; gt < 4; ++gt) acc_pre[gt] = MFMA(Axn, B0H[gt][0], acc_pre[gt]);
                #pragma unroll
                for (int gt = 0; gt < 4; ++gt) acc_pre[gt] = MFMA(Axn, B0L[gt][0], acc_pre[gt]);
            }
            if (ldx){
                const int row = (tid * 4) / 24, col = (tid * 4) % 24;
                ushort4 w = { f2bf(pref.x), f2bf(pref.y), f2bf(pref.z), f2bf(pref.w) };
                *reinterpret_cast<ushort4*>(&sXH[bxw][row][col]) = w;
            }
            // overwrite guard (conservative, proven in r10)
            if (t >= 3) wait_ge(&sync[5], t - 2);
            #pragma unroll
            for (int i = 0; i < 4; ++i)
                sH0H[pw][g * 4 + i][cg] = hh[i];
            gbar(&sync[0], &sync[2], &sync[4], t, ph, l);
            pr = pw;
            pw  = (pw  == 2) ? 0 : pw  + 1;
            bxr = (bxr == 2) ? 0 : bxr + 1;
            bxw = (bxw == 2) ? 0 : bxw + 1;
        }
    } else {
        // ================= LAYER 1 + head waves (group 1) =================
        bf16x8 B1H[4][4], B1L[4][4];   // ks0,1 = Wih1 (h0 in), ks2,3 = Whh1 (h1 fb)
        #pragma unroll
        for (int gt = 0; gt < 4; ++gt){
            const int c = gt * 64 + cg;
            #pragma unroll
            for (int ks = 0; ks < 2; ++ks){
                bf16x8 ch, cl;
                const float* pw = &Wih1[c * 64 + ks * 32 + g * 8];
                #pragma unroll
                for (int j = 0; j < 8; ++j){ unsigned short hh, ll; splitf(pw[j], hh, ll); ch[j]=(short)hh; cl[j]=(short)ll; }
                B1H[gt][ks] = ch; B1L[gt][ks] = cl;
            }
            #pragma unroll
            for (int ks = 0; ks < 2; ++ks){
                bf16x8 ch, cl;
                const float* pw = &Whh1[c * 64 + ks * 32 + g * 8];
                #pragma unroll
                for (int j = 0; j < 8; ++j){ unsigned short hh, ll; splitf(pw[j], hh, ll); ch[j]=(short)hh; cl[j]=(short)ll; }
                B1H[gt][2+ks] = ch; B1L[gt][2+ks] = cl;
            }
        }
        float b1[4];
        #pragma unroll
        for (int gt = 0; gt < 4; ++gt) b1[gt] = bih1[gt*64 + cg] + bhh1[gt*64 + cg];

        // head weights
        const int oc = lr;
        bf16x8 WoH[2], WoL[2];
        #pragma unroll
        for (int tt = 0; tt < 2; ++tt){
            bf16x8 bh = {0,0,0,0,0,0,0,0}, bl = {0,0,0,0,0,0,0,0};
            if (oc < NOUT){
                const float* pw = &Wout[oc * 64 + tt * 32 + g * 8];
                #pragma unroll
                for (int j = 0; j < 8; ++j){ unsigned short hh, ll; splitf(pw[j], hh, ll); bh[j]=(short)hh; bl[j]=(short)ll; }
            }
            WoH[tt] = bh; WoL[tt] = bl;
        }
        const float bo0 = (oc < NOUT) ? bout[oc] : 0.f;
        float* houtp = out + (size_t)(r0 + g * 4) * NOUT + oc;   // step 0 base

        // pre-loop: acc_pre for tick 1 = bias + input(h0_0) MFMAs
        f32x4 acc_pre[4];
        {
            wait_ge(&sync[4], 0);
            bf16x8 A0H[2];
            A0H[0] = ldfrag(&sH0H[0][lr][g*8]);
            A0H[1] = ldfrag(&sH0H[0][lr][32 + g*8]);
            #pragma unroll
            for (int gt = 0; gt < 4; ++gt){ f32x4 a = {b1[gt],b1[gt],b1[gt],b1[gt]}; acc_pre[gt] = a; }
            #pragma unroll
            for (int ks = 0; ks < 2; ++ks){
                #pragma unroll
                for (int gt = 0; gt < 4; ++gt) acc_pre[gt] = MFMA(A0H[ks], B1H[gt][ks], acc_pre[gt]);
                #pragma unroll
                for (int gt = 0; gt < 4; ++gt) acc_pre[gt] = MFMA(A0H[ks], B1L[gt][ks], acc_pre[gt]);
            }
        }

        float c1[4] = {0,0,0,0};
        int ph = 0;
        int pr0 = 1;   // h0 read buffer t%3 (pre-work at end of tick t), t starts 1
        for (int t = 1; t <= SEQ; ++t){
            const int p = t & 1;
            // critical path: h1_{t-2} frags -> 16 fb MFMAs -> nonlin -> write
            bf16x8 A1H[2];
            A1H[0] = ldfrag(&sH1H[p][lr][g*8]);
            A1H[1] = ldfrag(&sH1H[p][lr][32 + g*8]);
            f32x4 a1[4];
            #pragma unroll
            for (int gt = 0; gt < 4; ++gt) a1[gt] = acc_pre[gt];
            #pragma unroll
            for (int ks = 0; ks < 2; ++ks){
                #pragma unroll
                for (int gt = 0; gt < 4; ++gt) a1[gt] = MFMA(A1H[ks], B1H[gt][2+ks], a1[gt]);
                #pragma unroll
                for (int gt = 0; gt < 4; ++gt) a1[gt] = MFMA(A1H[ks], B1L[gt][2+ks], a1[gt]);
            }
            #pragma unroll
            for (int i = 0; i < 4; ++i){
                const float ig = sigf(a1[0][i]);
                const float fg = sigf(a1[1][i]);
                const float gg = tanhf_(a1[2][i]);
                const float og = sigf(a1[3][i]);
                c1[i] = fg * c1[i] + ig * gg;
                sH1H[p ^ 1][g * 4 + i][cg] = f2bf(og * tanhf_(c1[i]));
            }
            // head for step t-2: A1H == h1_{t-2} (live regs; lag-2, r10-proven)
            if (t >= 2 && w2 == (t & 3)){
                f32x4 ha = {bo0, bo0, bo0, bo0};
                ha = MFMA(A1H[0], WoH[0], ha);
                ha = MFMA(A1H[0], WoL[0], ha);
                ha = MFMA(A1H[1], WoH[1], ha);
                ha = MFMA(A1H[1], WoL[1], ha);
                if (oc < NOUT){
                    #pragma unroll
                    for (int i = 0; i < 4; ++i)
                        houtp[(size_t)i * NOUT] = ha[i];
                }
            }
            if (t >= 2) houtp += (size_t)BATCH * NOUT;
            // pre-work for tick t+1: input-side MFMAs on h0_t (l0 runs ahead)
            if (t < SEQ){
                wait_ge(&sync[4], t);
                bf16x8 A0H[2];
                A0H[0] = ldfrag(&sH0H[pr0][lr][g*8]);
                A0H[1] = ldfrag(&sH0H[pr0][lr][32 + g*8]);
                #pragma unroll
                for (int gt = 0; gt < 4; ++gt){ f32x4 a = {b1[gt],b1[gt],b1[gt],b1[gt]}; acc_pre[gt] = a; }
                #pragma unroll
                for (int ks = 0; ks < 2; ++ks){
                    #pragma unroll
                    for (int gt = 0; gt < 4; ++gt) acc_pre[gt] = MFMA(A0H[ks], B1H[gt][ks], acc_pre[gt]);
                    #pragma unroll
                    for (int gt = 0; gt < 4; ++gt) acc_pre[gt] = MFMA(A0H[ks], B1L[gt][ks], acc_pre[gt]);
                }
                pr0 = (pr0 == 2) ? 0 : pr0 + 1;
            }
            gbar(&sync[1], &sync[3], &sync[5], t, ph, l);
        }
        // epilogue: head for step SEQ-1 (h1_{SEQ-1} in sH1[(SEQ+1)&1], own-group)
        {
            const int pe = (SEQ + 1) & 1;
            if (w2 == ((SEQ + 1) & 3)){
                bf16x8 A1H0 = ldfrag(&sH1H[pe][lr][g*8]);
                bf16x8 A1H1 = ldfrag(&sH1H[pe][lr][32 + g*8]);
                f32x4 ha = {bo0, bo0, bo0, bo0};
                ha = MFMA(A1H0, WoH[0], ha);
                ha = MFMA(A1H0, WoL[0], ha);
                ha = MFMA(A1H1, WoH[1], ha);
                ha = MFMA(A1H1, WoL[1], ha);
                if (oc < NOUT){
                    #pragma unroll
                    for (int i = 0; i < 4; ++i)
                        houtp[(size_t)i * NOUT] = ha[i];
                }
            }
        }
    }
}

extern "C" void kernel_launch(void* const* d_in, const int* in_sizes, int n_in,
                              void* d_out, int out_size, void* d_ws, size_t ws_size,
                              hipStream_t stream)
{
    const float* x    = (const float*)d_in[0];
    const float* Wih0 = (const float*)d_in[1];
    const float* Whh0 = (const float*)d_in[2];
    const float* bih0 = (const float*)d_in[3];
    const float* bhh0 = (const float*)d_in[4];
    const float* Wih1 = (const float*)d_in[5];
    const float* Whh1 = (const float*)d_in[6];
    const float* bih1 = (const float*)d_in[7];
    const float* bhh1 = (const float*)d_in[8];
    const float* Wout = (const float*)d_in[9];
    const float* bout = (const float*)d_in[10];
    float* out = (float*)d_out;

    lstm_fused<<<NBLK, 512, 0, stream>>>(x, Wih0, Whh0, bih0, bhh0,
                                         Wih1, Whh1, bih1, bhh1,
                                         Wout, bout, out);
}

// Round 13
// 166.873 us; speedup vs baseline: 1.2803x; 1.2803x over previous
//
#include <hip/hip_runtime.h>
#include <hip/hip_bf16.h>
#include <math.h>

#define SEQ   168
#define BATCH 4096
#define NOUT  9
#define NBLK  256        // BATCH / 16

typedef short bf16x8 __attribute__((ext_vector_type(8)));
typedef float f32x4  __attribute__((ext_vector_type(4)));

#define MFMA(a,b,c) __builtin_amdgcn_mfma_f32_16x16x32_bf16((a),(b),(c),0,0,0)

static __device__ __forceinline__ float bf2f(unsigned short h){
    unsigned int u = ((unsigned int)h) << 16;
    return __builtin_bit_cast(float, u);
}
static __device__ __forceinline__ unsigned short f2bf(float f){  // HW RNE
    return __builtin_bit_cast(unsigned short, __float2bfloat16(f));
}
// 2-term split kept ONLY for the head weights (4 MFMAs, direct output impact)
static __device__ __forceinline__ void splitf(float f, unsigned short& hi, unsigned short& lo){
    hi = f2bf(f);
    float r = f - bf2f(hi);
    lo = (unsigned short)(__builtin_bit_cast(unsigned int, r) >> 16);
}
static __device__ __forceinline__ float sigf(float x){
    return __builtin_amdgcn_rcpf(1.0f + __expf(-x));
}
static __device__ __forceinline__ float tanhf_(float x){
    float r = __builtin_amdgcn_rcpf(1.0f + __expf(2.0f * x));
    return fmaf(-2.0f, r, 1.0f);
}
static __device__ __forceinline__ bf16x8 ldfrag(const unsigned short* p){
    const uint4 q = *reinterpret_cast<const uint4*>(p);
    return __builtin_bit_cast(bf16x8, q);
}

// group-local sense-reversing barrier over 4 waves; last arriver posts `tickval`
static __device__ __forceinline__ void gbar(int* cnt, int* phs, int* done,
                                            int tickval, int& ph, int lane){
    asm volatile("s_waitcnt lgkmcnt(0)" ::: "memory");
    if (lane == 0){
        int old = __hip_atomic_fetch_add(cnt, 1, __ATOMIC_ACQ_REL,
                                         __HIP_MEMORY_SCOPE_WORKGROUP);
        if (old == 3){
            *cnt = 0;
            __hip_atomic_store(done, tickval, __ATOMIC_RELEASE,
                               __HIP_MEMORY_SCOPE_WORKGROUP);
            __hip_atomic_store(phs, ph ^ 1, __ATOMIC_RELEASE,
                               __HIP_MEMORY_SCOPE_WORKGROUP);
        }
    }
    while (__hip_atomic_load(phs, __ATOMIC_ACQUIRE,
                             __HIP_MEMORY_SCOPE_WORKGROUP) == ph)
        __builtin_amdgcn_s_sleep(1);
    ph ^= 1;
}
static __device__ __forceinline__ void wait_ge(int* done, int need){
    if (__hip_atomic_load(done, __ATOMIC_ACQUIRE, __HIP_MEMORY_SCOPE_WORKGROUP) >= need) return;
    do { __builtin_amdgcn_s_sleep(1); }
    while (__hip_atomic_load(done, __ATOMIC_ACQUIRE, __HIP_MEMORY_SCOPE_WORKGROUP) < need);
}

// r10 schedule (proven 187 us), arithmetic reduced to 1-term bf16 gate weights.
//   Group 0 (waves 0-3): layer0 tick t in [0,SEQ): h0_t -> sH0[t%3].
//   Group 1 (waves 4-7): layer1 tick t in [1,SEQ]: step t-1 + head for step t-2
//     on a rotating wave reusing the live A1H frags; epilogue emits step SEQ-1.
// h0 triple-buffered: l0 overwrite-guard l1_done >= t-2; l1 read-guard
// l0_done >= t-1 -> groups decouple with ~1 tick of slack each way.
__global__ __launch_bounds__(512, 2)
void lstm_fused(const float* __restrict__ x,
                const float* __restrict__ Wih0, const float* __restrict__ Whh0,
                const float* __restrict__ bih0, const float* __restrict__ bhh0,
                const float* __restrict__ Wih1, const float* __restrict__ Whh1,
                const float* __restrict__ bih1, const float* __restrict__ bhh1,
                const float* __restrict__ Wout, const float* __restrict__ bout,
                float* __restrict__ out)
{
    __shared__ __align__(16) unsigned short sXH[2][16][72];   // x hi, stride 144B
    __shared__ __align__(16) unsigned short sH0H[3][16][72];  // h0 hi, triple buf
    __shared__ __align__(16) unsigned short sH1H[2][16][72];  // h1 hi
    __shared__ int sync[8];  // [0,1]=cnt, [2,3]=phase, [4]=l0_done, [5]=l1_done

    const int tid  = threadIdx.x;
    const int half = tid >> 8;
    const int w2   = (tid >> 6) & 3;
    const int l    = tid & 63;
    const int lr   = l & 15;
    const int g    = l >> 4;
    const int r0   = blockIdx.x * 16;
    const int cg   = w2 * 16 + lr;

    if (tid < 8) sync[tid] = (tid == 4) ? -1 : 0;

    for (int i = tid; i < (int)(2*16*72/2); i += 512){
        ((unsigned int*)sXH)[i]  = 0u;
        ((unsigned int*)sH1H)[i] = 0u;
    }
    for (int i = tid; i < (int)(3*16*72/2); i += 512)
        ((unsigned int*)sH0H)[i] = 0u;
    __syncthreads();
    // stage x_0 into buffer 0
    if (tid < 96){
        const float4 v = *reinterpret_cast<const float4*>(&x[(size_t)r0 * 24 + tid * 4]);
        const int row = (tid * 4) / 24, col = (tid * 4) % 24;
        ushort4 w = { f2bf(v.x), f2bf(v.y), f2bf(v.z), f2bf(v.w) };
        *reinterpret_cast<ushort4*>(&sXH[0][row][col]) = w;
    }
    __syncthreads();

    if (half == 0){
        // ================= LAYER 0 waves (group 0) =================
        bf16x8 B0H[4][3];   // ks0 = Wih0 (K=24 pad 32), ks1,2 = Whh0; 1-term bf16
        #pragma unroll
        for (int gt = 0; gt < 4; ++gt){
            const int c = gt * 64 + cg;
            bf16x8 bh = {0,0,0,0,0,0,0,0};
            if (g < 3){
                const float* pw = &Wih0[c * 24 + g * 8];
                #pragma unroll
                for (int j = 0; j < 8; ++j) bh[j] = (short)f2bf(pw[j]);
            }
            B0H[gt][0] = bh;
            #pragma unroll
            for (int ks = 0; ks < 2; ++ks){
                bf16x8 ch;
                const float* pw = &Whh0[c * 64 + ks * 32 + g * 8];
                #pragma unroll
                for (int j = 0; j < 8; ++j) ch[j] = (short)f2bf(pw[j]);
                B0H[gt][1+ks] = ch;
            }
        }
        float b0[4];
        #pragma unroll
        for (int gt = 0; gt < 4; ++gt) b0[gt] = bih0[gt*64 + cg] + bhh0[gt*64 + cg];

        const float* xfp = x + ((size_t)BATCH + r0) * 24 + tid * 4;  // x for tick t+1
        float c0[4] = {0,0,0,0};
        int ph = 0;
        int pw = 0, pr = 2;   // pw = t%3 (write h0_t), pr = (t-1)%3 (read h0_{t-1})
        for (int t = 0; t < SEQ; ++t){
            const int px = t & 1;
            const bool ldx = (tid < 96) && (t + 1 < SEQ);
            float4 pref;
            if (ldx){ pref = *reinterpret_cast<const float4*>(xfp); xfp += (size_t)BATCH * 24; }

            const bf16x8 AxH = ldfrag(&sXH[px][lr][g*8]);
            bf16x8 A0H[2];
            #pragma unroll
            for (int ks = 0; ks < 2; ++ks)
                A0H[ks] = ldfrag(&sH0H[pr][lr][ks*32 + g*8]);

            f32x4 a0[4];
            #pragma unroll
            for (int gt = 0; gt < 4; ++gt){ f32x4 a = {b0[gt],b0[gt],b0[gt],b0[gt]}; a0[gt] = a; }
            #pragma unroll
            for (int gt = 0; gt < 4; ++gt) a0[gt] = MFMA(AxH, B0H[gt][0], a0[gt]);
            #pragma unroll
            for (int ks = 0; ks < 2; ++ks){
                #pragma unroll
                for (int gt = 0; gt < 4; ++gt) a0[gt] = MFMA(A0H[ks], B0H[gt][1+ks], a0[gt]);
            }
            unsigned short hh[4];
            #pragma unroll
            for (int i = 0; i < 4; ++i){
                const float ig = sigf(a0[0][i]);
                const float fg = sigf(a0[1][i]);
                const float gg = tanhf_(a0[2][i]);
                const float og = sigf(a0[3][i]);
                c0[i] = fg * c0[i] + ig * gg;
                hh[i] = f2bf(og * tanhf_(c0[i]));
            }
            // overwrite guard: buffer pw holds h0_{t-3}, consumed by l1 at tick t-2
            if (t >= 3) wait_ge(&sync[5], t - 2);
            #pragma unroll
            for (int i = 0; i < 4; ++i)
                sH0H[pw][g * 4 + i][cg] = hh[i];
            if (ldx){
                const int row = (tid * 4) / 24, col = (tid * 4) % 24;
                ushort4 w = { f2bf(pref.x), f2bf(pref.y), f2bf(pref.z), f2bf(pref.w) };
                *reinterpret_cast<ushort4*>(&sXH[px ^ 1][row][col]) = w;
            }
            gbar(&sync[0], &sync[2], &sync[4], t, ph, l);
            pr = pw;
            pw = (pw == 2) ? 0 : pw + 1;
        }
    } else {
        // ================= LAYER 1 + head waves (group 1) =================
        bf16x8 B1H[4][4];   // ks0,1 = Wih1 (h0 in), ks2,3 = Whh1 (h1 fb); 1-term
        #pragma unroll
        for (int gt = 0; gt < 4; ++gt){
            const int c = gt * 64 + cg;
            #pragma unroll
            for (int ks = 0; ks < 2; ++ks){
                bf16x8 ch;
                const float* pw = &Wih1[c * 64 + ks * 32 + g * 8];
                #pragma unroll
                for (int j = 0; j < 8; ++j) ch[j] = (short)f2bf(pw[j]);
                B1H[gt][ks] = ch;
            }
            #pragma unroll
            for (int ks = 0; ks < 2; ++ks){
                bf16x8 ch;
                const float* pw = &Whh1[c * 64 + ks * 32 + g * 8];
                #pragma unroll
                for (int j = 0; j < 8; ++j) ch[j] = (short)f2bf(pw[j]);
                B1H[gt][2+ks] = ch;
            }
        }
        float b1[4];
        #pragma unroll
        for (int gt = 0; gt < 4; ++gt) b1[gt] = bih1[gt*64 + cg] + bhh1[gt*64 + cg];

        // head weights: keep hi+lo (4 MFMAs total, direct output impact)
        const int oc = lr;
        bf16x8 WoH[2], WoL[2];
        #pragma unroll
        for (int tt = 0; tt < 2; ++tt){
            bf16x8 bh = {0,0,0,0,0,0,0,0}, bl = {0,0,0,0,0,0,0,0};
            if (oc < NOUT){
                const float* pw = &Wout[oc * 64 + tt * 32 + g * 8];
                #pragma unroll
                for (int j = 0; j < 8; ++j){ unsigned short hh, ll; splitf(pw[j], hh, ll); bh[j]=(short)hh; bl[j]=(short)ll; }
            }
            WoH[tt] = bh; WoL[tt] = bl;
        }
        const float bo0 = (oc < NOUT) ? bout[oc] : 0.f;
        float* houtp = out + (size_t)(r0 + g * 4) * NOUT + oc;

        float c1[4] = {0,0,0,0};
        int ph = 0;
        int pr0 = 0;   // (t-1) % 3, starting at t=1
        for (int t = 1; t <= SEQ; ++t){
            const int p = t & 1;
            // own-group feedback frags (= h1_{t-2}, also the head's input)
            bf16x8 A1H[2];
            #pragma unroll
            for (int ks = 0; ks < 2; ++ks)
                A1H[ks] = ldfrag(&sH1H[p][lr][ks*32 + g*8]);
            // h0_{t-1} ready? (l0 runs ahead -> almost always satisfied)
            wait_ge(&sync[4], t - 1);
            bf16x8 A0H[2];
            #pragma unroll
            for (int ks = 0; ks < 2; ++ks)
                A0H[ks] = ldfrag(&sH0H[pr0][lr][ks*32 + g*8]);

            f32x4 a1[4];
            #pragma unroll
            for (int gt = 0; gt < 4; ++gt){ f32x4 a = {b1[gt],b1[gt],b1[gt],b1[gt]}; a1[gt] = a; }
            // feedback MFMAs first (A0 read latency hides underneath)
            #pragma unroll
            for (int ks = 0; ks < 2; ++ks){
                #pragma unroll
                for (int gt = 0; gt < 4; ++gt) a1[gt] = MFMA(A1H[ks], B1H[gt][2+ks], a1[gt]);
            }
            // head for step t-2: rotating wave, reuses A1H (no LDS reads, no waits)
            if (t >= 2 && w2 == (t & 3)){
                f32x4 ha = {bo0, bo0, bo0, bo0};
                ha = MFMA(A1H[0], WoH[0], ha);
                ha = MFMA(A1H[0], WoL[0], ha);
                ha = MFMA(A1H[1], WoH[1], ha);
                ha = MFMA(A1H[1], WoL[1], ha);
                if (oc < NOUT){
                    #pragma unroll
                    for (int i = 0; i < 4; ++i)
                        houtp[(size_t)i * NOUT] = ha[i];
                }
            }
            if (t >= 2) houtp += (size_t)BATCH * NOUT;
            // input-side MFMAs
            #pragma unroll
            for (int ks = 0; ks < 2; ++ks){
                #pragma unroll
                for (int gt = 0; gt < 4; ++gt) a1[gt] = MFMA(A0H[ks], B1H[gt][ks], a1[gt]);
            }
            #pragma unroll
            for (int i = 0; i < 4; ++i){
                const float ig = sigf(a1[0][i]);
                const float fg = sigf(a1[1][i]);
                const float gg = tanhf_(a1[2][i]);
                const float og = sigf(a1[3][i]);
                c1[i] = fg * c1[i] + ig * gg;
                sH1H[p ^ 1][g * 4 + i][cg] = f2bf(og * tanhf_(c1[i]));
            }
            gbar(&sync[1], &sync[3], &sync[5], t, ph, l);
            pr0 = (pr0 == 2) ? 0 : pr0 + 1;
        }
        // epilogue: head for step SEQ-1 (h1_{SEQ-1} in sH1[(SEQ+1)&1], stable)
        {
            const int pe = (SEQ + 1) & 1;
            if (w2 == ((SEQ + 1) & 3)){
                bf16x8 A1H0 = ldfrag(&sH1H[pe][lr][g*8]);
                bf16x8 A1H1 = ldfrag(&sH1H[pe][lr][32 + g*8]);
                f32x4 ha = {bo0, bo0, bo0, bo0};
                ha = MFMA(A1H0, WoH[0], ha);
                ha = MFMA(A1H0, WoL[0], ha);
                ha = MFMA(A1H1, WoH[1], ha);
                ha = MFMA(A1H1, WoL[1], ha);
                if (oc < NOUT){
                    #pragma unroll
                    for (int i = 0; i < 4; ++i)
                        houtp[(size_t)i * NOUT] = ha[i];
                }
            }
        }
    }
}

extern "C" void kernel_launch(void* const* d_in, const int* in_sizes, int n_in,
                              void* d_out, int out_size, void* d_ws, size_t ws_size,
                              hipStream_t stream)
{
    const float* x    = (const float*)d_in[0];
    const float* Wih0 = (const float*)d_in[1];
    const float* Whh0 = (const float*)d_in[2];
    const float* bih0 = (const float*)d_in[3];
    const float* bhh0 = (const float*)d_in[4];
    const float* Wih1 = (const float*)d_in[5];
    const float* Whh1 = (const float*)d_in[6];
    const float* bih1 = (const float*)d_in[7];
    const float* bhh1 = (const float*)d_in[8];
    const float* Wout = (const float*)d_in[9];
    const float* bout = (const float*)d_in[10];
    float* out = (float*)d_out;

    lstm_fused<<<NBLK, 512, 0, stream>>>(x, Wih0, Whh0, bih0, bhh0,
                                         Wih1, Whh1, bih1, bhh1,
                                         Wout, bout, out);
}